// Round 3
// baseline (331.786 us; speedup 1.0000x reference)
//
#include <hip/hip_runtime.h>
#include <hip/hip_bf16.h>
#include <cstddef>

typedef __attribute__((ext_vector_type(8))) short short8;
typedef __attribute__((ext_vector_type(4))) float f32x4;

__device__ inline unsigned short f2bf(float f) {
  unsigned int u = __float_as_uint(f);
  u += 0x7fffu + ((u >> 16) & 1u);
  return (unsigned short)(u >> 16);
}
__device__ inline unsigned int pkbf(float a, float b) {
  __hip_bfloat162 h = __float22bfloat162_rn(make_float2(a, b));
  union { __hip_bfloat162 h2; unsigned int u; } cv;
  cv.h2 = h;
  return cv.u;
}

// transpose + cast: src [R,C] f32 -> dst [C,R] bf16
__global__ __launch_bounds__(256) void tcast_kernel(const float* __restrict__ src,
                                                    unsigned short* __restrict__ dst,
                                                    int R, int C) {
  __shared__ float tile[64][65];
  int c0 = blockIdx.x * 64, r0 = blockIdx.y * 64;
  int tx = threadIdx.x & 63, ty = threadIdx.x >> 6;
  for (int i = ty; i < 64; i += 4)
    tile[i][tx] = src[(size_t)(r0 + i) * C + c0 + tx];
  __syncthreads();
  for (int i = ty; i < 64; i += 4)
    dst[(size_t)(c0 + i) * R + r0 + tx] = f2bf(tile[tx][i]);
}

// C = A[M,K] * Bt[N,K]^T. Block tile (MT*32) x 128, 4 waves 2x2, T14 prefetch.
// MODE 0: C0 bf16 [M,N] scaled by oscale
// MODE 1: split kv: col<512 -> C0 bf16 [M,512]; col>=512 -> C1 vt[b,h,d,m]
// MODE 2: C0 f32 [M,N] + bias
template <int MT, int MODE, bool AF32>
__global__ __launch_bounds__(256, 2) void gemm_kernel(
    const void* __restrict__ Ap, const unsigned short* __restrict__ Bt,
    void* __restrict__ C0, unsigned short* __restrict__ C1,
    const float* __restrict__ bias, int M, int N, int K, float oscale) {
  __shared__ unsigned short As[MT * 32][72];
  __shared__ unsigned short Bs[128][72];
  const int bm = blockIdx.y * (MT * 32), bn = blockIdx.x * 128;
  const int tid = threadIdx.x;
  const int wave = tid >> 6, lane = tid & 63;
  const int wr = (wave >> 1) * (MT * 16), wc = (wave & 1) * 64;
  const int l15 = lane & 15, lq = lane >> 4;
  const int sr = tid >> 3, sc = (tid & 7) * 8;
  f32x4 acc[MT][4] = {};

  const float* Af = (const float*)Ap;
  const unsigned short* Ab = (const unsigned short*)Ap;

  float4 fa[MT][2];
  uint4 ua[MT];
  uint4 ub[4];

  auto load_chunk = [&](int k0) {
#pragma unroll
    for (int p = 0; p < MT; ++p) {
      if constexpr (AF32) {
        fa[p][0] = *(const float4*)(Af + (size_t)(bm + sr + p * 32) * K + k0 + sc);
        fa[p][1] = *(const float4*)(Af + (size_t)(bm + sr + p * 32) * K + k0 + sc + 4);
      } else {
        ua[p] = *(const uint4*)(Ab + (size_t)(bm + sr + p * 32) * K + k0 + sc);
      }
    }
#pragma unroll
    for (int p = 0; p < 4; ++p)
      ub[p] = *(const uint4*)(Bt + (size_t)(bn + sr + p * 32) * K + k0 + sc);
  };

  load_chunk(0);

  for (int k0 = 0; k0 < K; k0 += 64) {
    __syncthreads();  // BAR-A: all prev-tile LDS reads done; vmcnt drain = our data
#pragma unroll
    for (int p = 0; p < MT; ++p) {
      if constexpr (AF32) {
        uint4 u;
        u.x = pkbf(fa[p][0].x, fa[p][0].y);
        u.y = pkbf(fa[p][0].z, fa[p][0].w);
        u.z = pkbf(fa[p][1].x, fa[p][1].y);
        u.w = pkbf(fa[p][1].z, fa[p][1].w);
        *(uint4*)(&As[sr + p * 32][sc]) = u;
      } else {
        *(uint4*)(&As[sr + p * 32][sc]) = ua[p];
      }
    }
#pragma unroll
    for (int p = 0; p < 4; ++p)
      *(uint4*)(&Bs[sr + p * 32][sc]) = ub[p];
    if (k0 + 64 < K) load_chunk(k0 + 64);  // async: lands during compute
    asm volatile("s_waitcnt lgkmcnt(0)" ::: "memory");
    __builtin_amdgcn_s_barrier();  // BAR-B (no vmcnt drain -> prefetch stays in flight)
#pragma unroll
    for (int kk = 0; kk < 2; ++kk) {
      short8 af[MT], bfr[4];
#pragma unroll
      for (int mt = 0; mt < MT; ++mt)
        af[mt] = *(const short8*)(&As[wr + mt * 16 + l15][kk * 32 + lq * 8]);
#pragma unroll
      for (int nt = 0; nt < 4; ++nt)
        bfr[nt] = *(const short8*)(&Bs[wc + nt * 16 + l15][kk * 32 + lq * 8]);
#pragma unroll
      for (int mt = 0; mt < MT; ++mt)
#pragma unroll
        for (int nt = 0; nt < 4; ++nt)
          acc[mt][nt] = __builtin_amdgcn_mfma_f32_16x16x32_bf16(af[mt], bfr[nt], acc[mt][nt], 0, 0, 0);
    }
  }

#pragma unroll
  for (int mt = 0; mt < MT; ++mt)
#pragma unroll
    for (int nt = 0; nt < 4; ++nt)
#pragma unroll
      for (int j = 0; j < 4; ++j) {
        int row = bm + wr + mt * 16 + lq * 4 + j;
        int col = bn + wc + nt * 16 + l15;
        float v = acc[mt][nt][j];
        if constexpr (MODE == 0) {
          ((unsigned short*)C0)[(size_t)row * N + col] = f2bf(v * oscale);
        } else if constexpr (MODE == 1) {
          if (col < 512) {
            ((unsigned short*)C0)[(size_t)row * 512 + col] = f2bf(v);
          } else {
            int bb = row >> 11, m = row & 2047;
            int hd = col - 512;  // h*64+d
            C1[((size_t)bb * 512 + hd) * 2048 + m] = f2bf(v);
          }
        } else {
          ((float*)C0)[(size_t)row * N + col] = v + bias[col];
        }
      }
}

// Flash attention, swapped-MFMA in-register softmax, T14 async staging.
// Q (pre-scaled by scale*log2e) / K: [B*2048, 512] bf16. Vt: [b,h,d,m] bf16.
// O: [B*2048, 512] bf16. 2 waves x 32 q-rows = 64 q-rows/block, KV tile 64.
// wave0 stages K tile, wave1 stages V tile; stage regs loaded one tile ahead.
__global__ __launch_bounds__(128, 2) void attn_kernel(
    const unsigned short* __restrict__ Q, const unsigned short* __restrict__ Kb,
    const unsigned short* __restrict__ Vt, const int* __restrict__ mask,
    unsigned short* __restrict__ O) {
  __shared__ unsigned short Ks[64][72];
  __shared__ unsigned short Vs[64][72];
  const int b = blockIdx.y >> 3, h = blockIdx.y & 7;
  const int tid = threadIdx.x, wave = tid >> 6, lane = tid & 63;
  const int l15 = lane & 15, lq = lane >> 4;
  const int wrow = blockIdx.x * 64 + wave * 32;

  // Q fragments: lane holds q-col = l15, d-elems lq*8..+7
  short8 qf[2][2];
#pragma unroll
  for (int rt = 0; rt < 2; ++rt)
#pragma unroll
    for (int kk = 0; kk < 2; ++kk)
      qf[rt][kk] = *(const short8*)(Q + (size_t)(b * 2048 + wrow + rt * 16 + l15) * 512
                                      + h * 64 + kk * 32 + lq * 8);

  f32x4 o[2][4] = {};  // O^T[d = dt*16+lq*4+j][q = rt*16+l15]
  float mrun[2] = {-1e30f, -1e30f}, lrun[2] = {0.f, 0.f};

  const unsigned short* Kg = Kb + (size_t)b * 2048 * 512 + h * 64;
  const unsigned short* Vg = Vt + (size_t)(b * 8 + h) * 64 * 2048;
  const int* mg = mask + b * 2048;

  const int srow = lane >> 3;       // 0..7
  const int scol = (lane & 7) * 8;  // elem col within 64

  uint4 sreg[8];
  int4 mi[4];

  auto stage_load = [&](int mb) {
    if (wave == 0) {
#pragma unroll
      for (int i = 0; i < 8; ++i)
        sreg[i] = *(const uint4*)(Kg + (size_t)(mb + i * 8 + srow) * 512 + scol);
    } else {
#pragma unroll
      for (int i = 0; i < 8; ++i)
        sreg[i] = *(const uint4*)(Vg + (size_t)(i * 8 + srow) * 2048 + mb + scol);
    }
#pragma unroll
    for (int ct = 0; ct < 4; ++ct)
      mi[ct] = *(const int4*)(mg + mb + ct * 16 + lq * 4);
  };

  stage_load(0);

  for (int mb = 0; mb < 2048; mb += 64) {
    __syncthreads();  // BAR-A: prev compute's LDS reads done; drains our stage loads (needed now)
    if (wave == 0) {
#pragma unroll
      for (int i = 0; i < 8; ++i)
        *(uint4*)(&Ks[i * 8 + srow][scol]) = sreg[i];
    } else {
#pragma unroll
      for (int i = 0; i < 8; ++i)
        *(uint4*)(&Vs[i * 8 + srow][scol]) = sreg[i];
    }
    // mask regs -> additive bias (before mi is overwritten by next prefetch)
    f32x4 maf[4];
#pragma unroll
    for (int ct = 0; ct < 4; ++ct) {
      maf[ct][0] = mi[ct].x ? 0.f : -1e30f;
      maf[ct][1] = mi[ct].y ? 0.f : -1e30f;
      maf[ct][2] = mi[ct].z ? 0.f : -1e30f;
      maf[ct][3] = mi[ct].w ? 0.f : -1e30f;
    }
    if (mb + 64 < 2048) stage_load(mb + 64);  // async prefetch, lands during compute
    asm volatile("s_waitcnt lgkmcnt(0)" ::: "memory");
    __builtin_amdgcn_s_barrier();  // BAR-B: LDS tile visible; prefetch stays in flight

    // swapped QK^T: s[rt][ct] = S^T[key = ct*16+lq*4+j][q = rt*16+l15]
    f32x4 s[2][4] = {};
#pragma unroll
    for (int kk = 0; kk < 2; ++kk) {
      short8 kf[4];
#pragma unroll
      for (int ct = 0; ct < 4; ++ct)
        kf[ct] = *(const short8*)(&Ks[ct * 16 + l15][kk * 32 + lq * 8]);
#pragma unroll
      for (int rt = 0; rt < 2; ++rt)
#pragma unroll
        for (int ct = 0; ct < 4; ++ct)
          s[rt][ct] = __builtin_amdgcn_mfma_f32_16x16x32_bf16(kf[ct], qf[rt][kk], s[rt][ct], 0, 0, 0);
    }

    unsigned int pf[2][2][4];  // [rt][kk][reg]
#pragma unroll
    for (int rt = 0; rt < 2; ++rt) {
      float t = -1e30f;
#pragma unroll
      for (int ct = 0; ct < 4; ++ct)
#pragma unroll
        for (int j = 0; j < 4; ++j) {
          s[rt][ct][j] += maf[ct][j];
          t = fmaxf(t, s[rt][ct][j]);
        }
      t = fmaxf(t, __shfl_xor(t, 16));
      t = fmaxf(t, __shfl_xor(t, 32));
      float mn = fmaxf(mrun[rt], t);
      float fac = __builtin_amdgcn_exp2f(mrun[rt] - mn);
      mrun[rt] = mn;
      float rs = 0.f;
      unsigned int xp[4][2];  // bf16 pairs: keys ct*16+lq*4+{2p,2p+1}
#pragma unroll
      for (int ct = 0; ct < 4; ++ct) {
        float p0 = __builtin_amdgcn_exp2f(s[rt][ct][0] - mn);
        float p1 = __builtin_amdgcn_exp2f(s[rt][ct][1] - mn);
        float p2 = __builtin_amdgcn_exp2f(s[rt][ct][2] - mn);
        float p3 = __builtin_amdgcn_exp2f(s[rt][ct][3] - mn);
        rs += (p0 + p1) + (p2 + p3);
        xp[ct][0] = pkbf(p0, p1);
        xp[ct][1] = pkbf(p2, p3);
      }
      rs += __shfl_xor(rs, 16);
      rs += __shfl_xor(rs, 32);
      lrun[rt] = lrun[rt] * fac + rs;
#pragma unroll
      for (int dt = 0; dt < 4; ++dt)
#pragma unroll
        for (int j = 0; j < 4; ++j)
          o[rt][dt][j] *= fac;

      // redistribute P^T into PV B-fragments:
      // dest reg r needs xp[kk*2 + (lq>>1)][r&1] from lane ((lq&1)*2 + (r>>1))*16 + l15
      const int slbase = ((lq & 1) * 2) * 16 + l15;
#pragma unroll
      for (int kk = 0; kk < 2; ++kk)
#pragma unroll
        for (int r = 0; r < 4; ++r) {
          int sl = (slbase + (r >> 1) * 16) << 2;
          unsigned a0 = (unsigned)__builtin_amdgcn_ds_bpermute(sl, (int)xp[kk * 2 + 0][r & 1]);
          unsigned a1 = (unsigned)__builtin_amdgcn_ds_bpermute(sl, (int)xp[kk * 2 + 1][r & 1]);
          pf[rt][kk][r] = (lq >> 1) ? a1 : a0;
        }
    }

    // PV swapped: O^T += V^T · P^T
#pragma unroll
    for (int kk = 0; kk < 2; ++kk)
#pragma unroll
      for (int dt = 0; dt < 4; ++dt) {
        short8 vf = *(const short8*)(&Vs[dt * 16 + l15][kk * 32 + lq * 8]);
#pragma unroll
        for (int rt = 0; rt < 2; ++rt) {
          union { unsigned int u[4]; short8 s8; } pc;
          pc.u[0] = pf[rt][kk][0];
          pc.u[1] = pf[rt][kk][1];
          pc.u[2] = pf[rt][kk][2];
          pc.u[3] = pf[rt][kk][3];
          o[rt][dt] = __builtin_amdgcn_mfma_f32_16x16x32_bf16(vf, pc.s8, o[rt][dt], 0, 0, 0);
        }
      }
  }

#pragma unroll
  for (int rt = 0; rt < 2; ++rt) {
    float rl = 1.0f / lrun[rt];
    unsigned short* Orow = O + (size_t)(b * 2048 + wrow + rt * 16 + l15) * 512 + h * 64;
#pragma unroll
    for (int dt = 0; dt < 4; ++dt) {
      *(unsigned int*)(Orow + dt * 16 + lq * 4)     = pkbf(o[rt][dt][0] * rl, o[rt][dt][1] * rl);
      *(unsigned int*)(Orow + dt * 16 + lq * 4 + 2) = pkbf(o[rt][dt][2] * rl, o[rt][dt][3] * rl);
    }
  }
}

extern "C" void kernel_launch(void* const* d_in, const int* in_sizes, int n_in,
                              void* d_out, int out_size, void* d_ws, size_t ws_size,
                              hipStream_t stream) {
  const float* x       = (const float*)d_in[0];
  const float* context = (const float*)d_in[1];
  const int*   mask    = (const int*)d_in[2];
  const float* Wq      = (const float*)d_in[3];
  const float* Wkv     = (const float*)d_in[4];
  const float* Wo      = (const float*)d_in[5];
  const float* bo      = (const float*)d_in[6];
  float* out = (float*)d_out;

  char* ws = (char*)d_ws;
  unsigned short* Wq_t  = (unsigned short*)(ws + 0);         //  512x512  bf16
  unsigned short* Wkv_t = (unsigned short*)(ws + 524288);    // 1024x512  bf16
  unsigned short* Wo_t  = (unsigned short*)(ws + 1572864);   //  512x512  bf16
  unsigned short* qb    = (unsigned short*)(ws + 2097152);   // 8192x512  bf16
  unsigned short* kb    = (unsigned short*)(ws + 10485760);  // 8192x512  bf16
  unsigned short* vtb   = (unsigned short*)(ws + 18874368);  // (b,h,d)x2048 bf16
  unsigned short* ab    = (unsigned short*)(ws + 27262976);  // 8192x512  bf16

  const float QSCALE = 0.125f * 1.44269504088896f;  // head_dim^-0.5 * log2(e)

  tcast_kernel<<<dim3(8, 8), 256, 0, stream>>>(Wq, Wq_t, 512, 512);
  tcast_kernel<<<dim3(16, 8), 256, 0, stream>>>(Wkv, Wkv_t, 512, 1024);
  tcast_kernel<<<dim3(8, 8), 256, 0, stream>>>(Wo, Wo_t, 512, 512);
  gemm_kernel<2, 0, true><<<dim3(4, 128), 256, 0, stream>>>(x, Wq_t, qb, nullptr, nullptr, 8192, 512, 512, QSCALE);
  gemm_kernel<4, 1, true><<<dim3(8, 64), 256, 0, stream>>>(context, Wkv_t, kb, vtb, nullptr, 8192, 1024, 512, 1.0f);
  attn_kernel<<<dim3(32, 32), 128, 0, stream>>>(qb, kb, vtb, mask, ab);
  gemm_kernel<2, 2, false><<<dim3(4, 128), 256, 0, stream>>>(ab, Wo_t, out, nullptr, bo, 8192, 512, 512, 1.0f);
}

// Round 4
// 291.693 us; speedup vs baseline: 1.1374x; 1.1374x over previous
//
#include <hip/hip_runtime.h>
#include <hip/hip_bf16.h>
#include <cstddef>

typedef __attribute__((ext_vector_type(8))) short short8;
typedef __attribute__((ext_vector_type(4))) float f32x4;

__device__ inline unsigned short f2bf(float f) {
  unsigned int u = __float_as_uint(f);
  u += 0x7fffu + ((u >> 16) & 1u);
  return (unsigned short)(u >> 16);
}
__device__ inline unsigned int pkbf(float a, float b) {
  __hip_bfloat162 h = __float22bfloat162_rn(make_float2(a, b));
  union { __hip_bfloat162 h2; unsigned int u; } cv;
  cv.h2 = h;
  return cv.u;
}

// transpose + cast: src [R,C] f32 -> dst [C,R] bf16
__global__ __launch_bounds__(256) void tcast_kernel(const float* __restrict__ src,
                                                    unsigned short* __restrict__ dst,
                                                    int R, int C) {
  __shared__ float tile[64][65];
  int c0 = blockIdx.x * 64, r0 = blockIdx.y * 64;
  int tx = threadIdx.x & 63, ty = threadIdx.x >> 6;
  for (int i = ty; i < 64; i += 4)
    tile[i][tx] = src[(size_t)(r0 + i) * C + c0 + tx];
  __syncthreads();
  for (int i = ty; i < 64; i += 4)
    dst[(size_t)(c0 + i) * R + r0 + tx] = f2bf(tile[tx][i]);
}

// C = A[M,K] * Bt[N,K]^T. Block tile (MT*32) x 128, 4 waves 2x2, T14 prefetch.
// MODE 0: C0 bf16 [M,N] scaled by oscale
// MODE 1: split kv: col<512 -> C0 bf16 [M,512]; col>=512 -> C1 vt[b,h,d,m]
// MODE 2: C0 f32 [M,N] + bias
template <int MT, int MODE, bool AF32>
__global__ __launch_bounds__(256, 2) void gemm_kernel(
    const void* __restrict__ Ap, const unsigned short* __restrict__ Bt,
    void* __restrict__ C0, unsigned short* __restrict__ C1,
    const float* __restrict__ bias, int M, int N, int K, float oscale) {
  __shared__ unsigned short As[MT * 32][72];
  __shared__ unsigned short Bs[128][72];
  const int bm = blockIdx.y * (MT * 32), bn = blockIdx.x * 128;
  const int tid = threadIdx.x;
  const int wave = tid >> 6, lane = tid & 63;
  const int wr = (wave >> 1) * (MT * 16), wc = (wave & 1) * 64;
  const int l15 = lane & 15, lq = lane >> 4;
  const int sr = tid >> 3, sc = (tid & 7) * 8;
  f32x4 acc[MT][4] = {};

  const float* Af = (const float*)Ap;
  const unsigned short* Ab = (const unsigned short*)Ap;

  float4 fa[MT][2];
  uint4 ua[MT];
  uint4 ub[4];

  auto load_chunk = [&](int k0) {
#pragma unroll
    for (int p = 0; p < MT; ++p) {
      if constexpr (AF32) {
        fa[p][0] = *(const float4*)(Af + (size_t)(bm + sr + p * 32) * K + k0 + sc);
        fa[p][1] = *(const float4*)(Af + (size_t)(bm + sr + p * 32) * K + k0 + sc + 4);
      } else {
        ua[p] = *(const uint4*)(Ab + (size_t)(bm + sr + p * 32) * K + k0 + sc);
      }
    }
#pragma unroll
    for (int p = 0; p < 4; ++p)
      ub[p] = *(const uint4*)(Bt + (size_t)(bn + sr + p * 32) * K + k0 + sc);
  };

  load_chunk(0);

  for (int k0 = 0; k0 < K; k0 += 64) {
    __syncthreads();  // BAR-A: prev-tile LDS reads done; vmcnt drain = our staged data
#pragma unroll
    for (int p = 0; p < MT; ++p) {
      if constexpr (AF32) {
        uint4 u;
        u.x = pkbf(fa[p][0].x, fa[p][0].y);
        u.y = pkbf(fa[p][0].z, fa[p][0].w);
        u.z = pkbf(fa[p][1].x, fa[p][1].y);
        u.w = pkbf(fa[p][1].z, fa[p][1].w);
        *(uint4*)(&As[sr + p * 32][sc]) = u;
      } else {
        *(uint4*)(&As[sr + p * 32][sc]) = ua[p];
      }
    }
#pragma unroll
    for (int p = 0; p < 4; ++p)
      *(uint4*)(&Bs[sr + p * 32][sc]) = ub[p];
    if (k0 + 64 < K) load_chunk(k0 + 64);  // prefetch: lands during compute
    asm volatile("s_waitcnt lgkmcnt(0)" ::: "memory");
    __builtin_amdgcn_s_barrier();  // BAR-B (no vmcnt drain -> prefetch stays in flight)
#pragma unroll
    for (int kk = 0; kk < 2; ++kk) {
      short8 af[MT], bfr[4];
#pragma unroll
      for (int mt = 0; mt < MT; ++mt)
        af[mt] = *(const short8*)(&As[wr + mt * 16 + l15][kk * 32 + lq * 8]);
#pragma unroll
      for (int nt = 0; nt < 4; ++nt)
        bfr[nt] = *(const short8*)(&Bs[wc + nt * 16 + l15][kk * 32 + lq * 8]);
#pragma unroll
      for (int mt = 0; mt < MT; ++mt)
#pragma unroll
        for (int nt = 0; nt < 4; ++nt)
          acc[mt][nt] = __builtin_amdgcn_mfma_f32_16x16x32_bf16(af[mt], bfr[nt], acc[mt][nt], 0, 0, 0);
    }
  }

#pragma unroll
  for (int mt = 0; mt < MT; ++mt)
#pragma unroll
    for (int nt = 0; nt < 4; ++nt)
#pragma unroll
      for (int j = 0; j < 4; ++j) {
        int row = bm + wr + mt * 16 + lq * 4 + j;
        int col = bn + wc + nt * 16 + l15;
        float v = acc[mt][nt][j];
        if constexpr (MODE == 0) {
          ((unsigned short*)C0)[(size_t)row * N + col] = f2bf(v * oscale);
        } else if constexpr (MODE == 1) {
          if (col < 512) {
            ((unsigned short*)C0)[(size_t)row * 512 + col] = f2bf(v);
          } else {
            int bb = row >> 11, m = row & 2047;
            int hd = col - 512;  // h*64+d
            C1[((size_t)bb * 512 + hd) * 2048 + m] = f2bf(v);
          }
        } else {
          ((float*)C0)[(size_t)row * N + col] = v + bias[col];
        }
      }
}

// Flash attention, swapped-MFMA in-register softmax, T14 async staging.
// Q (pre-scaled by scale*log2e) / K: [B*2048, 512] bf16. Vt: [b,h,d,m] bf16.
// O: [B*2048, 512] bf16.
// 4 waves x 16 q-rows = 64 q-rows/block, KV tile 64; 256 threads.
// blockIdx.x = bh (fast-varying -> per-XCD K/V L2 residency), blockIdx.y = q-chunk.
__global__ __launch_bounds__(256, 4) void attn_kernel(
    const unsigned short* __restrict__ Q, const unsigned short* __restrict__ Kb,
    const unsigned short* __restrict__ Vt, const int* __restrict__ mask,
    unsigned short* __restrict__ O) {
  __shared__ unsigned short Ks[64][72];
  __shared__ unsigned short Vs[64][72];
  const int b = blockIdx.x >> 3, h = blockIdx.x & 7;
  const int tid = threadIdx.x, wave = tid >> 6, lane = tid & 63;
  const int l15 = lane & 15, lq = lane >> 4;
  const int wrow = blockIdx.y * 64 + wave * 16;

  // Q fragments: lane holds q-col = l15, d-elems lq*8..+7
  short8 qf[2];
#pragma unroll
  for (int kk = 0; kk < 2; ++kk)
    qf[kk] = *(const short8*)(Q + (size_t)(b * 2048 + wrow + l15) * 512
                                + h * 64 + kk * 32 + lq * 8);

  f32x4 o[4] = {};  // O^T[d = dt*16+lq*4+j][q = l15]
  float mrun = -1e30f, lrun = 0.f;

  const unsigned short* Kg = Kb + (size_t)b * 2048 * 512 + h * 64;
  const unsigned short* Vg = Vt + (size_t)(b * 8 + h) * 64 * 2048;
  const int* mg = mask + b * 2048;

  const int str = tid >> 3;        // 0..31
  const int stc = (tid & 7) * 8;   // elem col within 64

  uint4 kreg[2], vreg[2];
  int4 mi[4];

  auto stage_load = [&](int mb) {
#pragma unroll
    for (int i = 0; i < 2; ++i)
      kreg[i] = *(const uint4*)(Kg + (size_t)(mb + str + i * 32) * 512 + stc);
#pragma unroll
    for (int i = 0; i < 2; ++i)
      vreg[i] = *(const uint4*)(Vg + (size_t)(str + i * 32) * 2048 + mb + stc);
#pragma unroll
    for (int ct = 0; ct < 4; ++ct)
      mi[ct] = *(const int4*)(mg + mb + ct * 16 + lq * 4);
  };

  stage_load(0);

  for (int mb = 0; mb < 2048; mb += 64) {
    __syncthreads();  // BAR-A: prev compute's LDS reads done; drains our staged loads
#pragma unroll
    for (int i = 0; i < 2; ++i)
      *(uint4*)(&Ks[str + i * 32][stc]) = kreg[i];
#pragma unroll
    for (int i = 0; i < 2; ++i)
      *(uint4*)(&Vs[str + i * 32][stc]) = vreg[i];
    // mask regs -> additive bias (before mi is overwritten by next prefetch)
    f32x4 maf[4];
#pragma unroll
    for (int ct = 0; ct < 4; ++ct) {
      maf[ct][0] = mi[ct].x ? 0.f : -1e30f;
      maf[ct][1] = mi[ct].y ? 0.f : -1e30f;
      maf[ct][2] = mi[ct].z ? 0.f : -1e30f;
      maf[ct][3] = mi[ct].w ? 0.f : -1e30f;
    }
    if (mb + 64 < 2048) stage_load(mb + 64);  // prefetch, lands during compute
    asm volatile("s_waitcnt lgkmcnt(0)" ::: "memory");
    __builtin_amdgcn_s_barrier();  // BAR-B: tile visible; prefetch stays in flight

    // swapped QK^T: s[ct] = S^T[key = ct*16+lq*4+j][q = l15]
    f32x4 s[4] = {};
#pragma unroll
    for (int kk = 0; kk < 2; ++kk) {
      short8 kf[4];
#pragma unroll
      for (int ct = 0; ct < 4; ++ct)
        kf[ct] = *(const short8*)(&Ks[ct * 16 + l15][kk * 32 + lq * 8]);
#pragma unroll
      for (int ct = 0; ct < 4; ++ct)
        s[ct] = __builtin_amdgcn_mfma_f32_16x16x32_bf16(kf[ct], qf[kk], s[ct], 0, 0, 0);
    }

    float t = -1e30f;
#pragma unroll
    for (int ct = 0; ct < 4; ++ct)
#pragma unroll
      for (int j = 0; j < 4; ++j) {
        s[ct][j] += maf[ct][j];
        t = fmaxf(t, s[ct][j]);
      }
    t = fmaxf(t, __shfl_xor(t, 16));
    t = fmaxf(t, __shfl_xor(t, 32));
    float mn = fmaxf(mrun, t);
    float fac = __builtin_amdgcn_exp2f(mrun - mn);
    mrun = mn;
    float rs = 0.f;
    unsigned int xp[4][2];  // bf16 pairs: keys ct*16+lq*4+{2p,2p+1}
#pragma unroll
    for (int ct = 0; ct < 4; ++ct) {
      float p0 = __builtin_amdgcn_exp2f(s[ct][0] - mn);
      float p1 = __builtin_amdgcn_exp2f(s[ct][1] - mn);
      float p2 = __builtin_amdgcn_exp2f(s[ct][2] - mn);
      float p3 = __builtin_amdgcn_exp2f(s[ct][3] - mn);
      rs += (p0 + p1) + (p2 + p3);
      xp[ct][0] = pkbf(p0, p1);
      xp[ct][1] = pkbf(p2, p3);
    }
    rs += __shfl_xor(rs, 16);
    rs += __shfl_xor(rs, 32);
    lrun = lrun * fac + rs;
#pragma unroll
    for (int dt = 0; dt < 4; ++dt)
#pragma unroll
      for (int j = 0; j < 4; ++j)
        o[dt][j] *= fac;

    // redistribute P^T into PV B-fragments:
    // dest reg r needs xp[kk*2 + (lq>>1)][r&1] from lane ((lq&1)*2 + (r>>1))*16 + l15
    unsigned int pf[2][4];
    const int slbase = ((lq & 1) * 2) * 16 + l15;
#pragma unroll
    for (int kk = 0; kk < 2; ++kk)
#pragma unroll
      for (int r = 0; r < 4; ++r) {
        int sl = (slbase + (r >> 1) * 16) << 2;
        unsigned a0 = (unsigned)__builtin_amdgcn_ds_bpermute(sl, (int)xp[kk * 2 + 0][r & 1]);
        unsigned a1 = (unsigned)__builtin_amdgcn_ds_bpermute(sl, (int)xp[kk * 2 + 1][r & 1]);
        pf[kk][r] = (lq >> 1) ? a1 : a0;
      }

    // PV swapped: O^T += V^T · P^T
#pragma unroll
    for (int kk = 0; kk < 2; ++kk) {
      union { unsigned int u[4]; short8 s8; } pc;
      pc.u[0] = pf[kk][0];
      pc.u[1] = pf[kk][1];
      pc.u[2] = pf[kk][2];
      pc.u[3] = pf[kk][3];
#pragma unroll
      for (int dt = 0; dt < 4; ++dt) {
        short8 vf = *(const short8*)(&Vs[dt * 16 + l15][kk * 32 + lq * 8]);
        o[dt] = __builtin_amdgcn_mfma_f32_16x16x32_bf16(vf, pc.s8, o[dt], 0, 0, 0);
      }
    }
  }

  float rl = 1.0f / lrun;
  unsigned short* Orow = O + (size_t)(b * 2048 + wrow + l15) * 512 + h * 64;
#pragma unroll
  for (int dt = 0; dt < 4; ++dt) {
    *(unsigned int*)(Orow + dt * 16 + lq * 4)     = pkbf(o[dt][0] * rl, o[dt][1] * rl);
    *(unsigned int*)(Orow + dt * 16 + lq * 4 + 2) = pkbf(o[dt][2] * rl, o[dt][3] * rl);
  }
}

extern "C" void kernel_launch(void* const* d_in, const int* in_sizes, int n_in,
                              void* d_out, int out_size, void* d_ws, size_t ws_size,
                              hipStream_t stream) {
  const float* x       = (const float*)d_in[0];
  const float* context = (const float*)d_in[1];
  const int*   mask    = (const int*)d_in[2];
  const float* Wq      = (const float*)d_in[3];
  const float* Wkv     = (const float*)d_in[4];
  const float* Wo      = (const float*)d_in[5];
  const float* bo      = (const float*)d_in[6];
  float* out = (float*)d_out;

  char* ws = (char*)d_ws;
  unsigned short* Wq_t  = (unsigned short*)(ws + 0);         //  512x512  bf16
  unsigned short* Wkv_t = (unsigned short*)(ws + 524288);    // 1024x512  bf16
  unsigned short* Wo_t  = (unsigned short*)(ws + 1572864);   //  512x512  bf16
  unsigned short* qb    = (unsigned short*)(ws + 2097152);   // 8192x512  bf16
  unsigned short* kb    = (unsigned short*)(ws + 10485760);  // 8192x512  bf16
  unsigned short* vtb   = (unsigned short*)(ws + 18874368);  // (b,h,d)x2048 bf16
  unsigned short* ab    = (unsigned short*)(ws + 27262976);  // 8192x512  bf16

  const float QSCALE = 0.125f * 1.44269504088896f;  // head_dim^-0.5 * log2(e)

  tcast_kernel<<<dim3(8, 8), 256, 0, stream>>>(Wq, Wq_t, 512, 512);
  tcast_kernel<<<dim3(16, 8), 256, 0, stream>>>(Wkv, Wkv_t, 512, 1024);
  tcast_kernel<<<dim3(8, 8), 256, 0, stream>>>(Wo, Wo_t, 512, 512);
  gemm_kernel<2, 0, true><<<dim3(4, 128), 256, 0, stream>>>(x, Wq_t, qb, nullptr, nullptr, 8192, 512, 512, QSCALE);
  gemm_kernel<2, 1, true><<<dim3(8, 128), 256, 0, stream>>>(context, Wkv_t, kb, vtb, nullptr, 8192, 1024, 512, 1.0f);
  attn_kernel<<<dim3(32, 32), 256, 0, stream>>>(qb, kb, vtb, mask, ab);
  gemm_kernel<2, 2, false><<<dim3(4, 128), 256, 0, stream>>>(ab, Wo_t, out, nullptr, bo, 8192, 512, 512, 1.0f);
}

// Round 5
// 261.547 us; speedup vs baseline: 1.2686x; 1.1153x over previous
//
#include <hip/hip_runtime.h>
#include <hip/hip_bf16.h>
#include <cstddef>

typedef __attribute__((ext_vector_type(8))) short short8;
typedef __attribute__((ext_vector_type(4))) float f32x4;

__device__ inline unsigned short f2bf(float f) {
  unsigned int u = __float_as_uint(f);
  u += 0x7fffu + ((u >> 16) & 1u);
  return (unsigned short)(u >> 16);
}
__device__ inline unsigned int pkbf(float a, float b) {
  __hip_bfloat162 h = __float22bfloat162_rn(make_float2(a, b));
  union { __hip_bfloat162 h2; unsigned int u; } cv;
  cv.h2 = h;
  return cv.u;
}

// transpose + cast: src [R,C] f32 -> dst [C,R] bf16
__global__ __launch_bounds__(256) void tcast_kernel(const float* __restrict__ src,
                                                    unsigned short* __restrict__ dst,
                                                    int R, int C) {
  __shared__ float tile[64][65];
  int c0 = blockIdx.x * 64, r0 = blockIdx.y * 64;
  int tx = threadIdx.x & 63, ty = threadIdx.x >> 6;
  for (int i = ty; i < 64; i += 4)
    tile[i][tx] = src[(size_t)(r0 + i) * C + c0 + tx];
  __syncthreads();
  for (int i = ty; i < 64; i += 4)
    dst[(size_t)(c0 + i) * R + r0 + tx] = f2bf(tile[tx][i]);
}

// pack key mask into 64-bit words: mpk[g] bit i = (mask[g*64+i] != 0)
__global__ __launch_bounds__(64) void maskpack_kernel(const int* __restrict__ mask,
                                                      unsigned long long* __restrict__ mpk) {
  int gid = blockIdx.x * 64 + threadIdx.x;
  unsigned long long bal = __ballot(mask[gid] != 0);
  if (threadIdx.x == 0) mpk[blockIdx.x] = bal;
}

// C = A[M,K] * Bt[N,K]^T. Block tile (MT*32) x 128, 4 waves 2x2, T14 prefetch.
// MODE 0: C0 bf16 [M,N] scaled by oscale
// MODE 1: split kv: col<512 -> C0 bf16 [M,512]; col>=512 -> C1 vt[b,h,d,m]
// MODE 2: C0 f32 [M,N] + bias
template <int MT, int MODE, bool AF32>
__global__ __launch_bounds__(256) void gemm_kernel(
    const void* __restrict__ Ap, const unsigned short* __restrict__ Bt,
    void* __restrict__ C0, unsigned short* __restrict__ C1,
    const float* __restrict__ bias, int M, int N, int K, float oscale) {
  __shared__ unsigned short As[MT * 32][72];
  __shared__ unsigned short Bs[128][72];
  const int bm = blockIdx.y * (MT * 32), bn = blockIdx.x * 128;
  const int tid = threadIdx.x;
  const int wave = tid >> 6, lane = tid & 63;
  const int wr = (wave >> 1) * (MT * 16), wc = (wave & 1) * 64;
  const int l15 = lane & 15, lq = lane >> 4;
  const int sr = tid >> 3, sc = (tid & 7) * 8;
  f32x4 acc[MT][4] = {};

  const float* Af = (const float*)Ap;
  const unsigned short* Ab = (const unsigned short*)Ap;

  float4 fa[MT][2];
  uint4 ua[MT];
  uint4 ub[4];

  auto load_chunk = [&](int k0) {
#pragma unroll
    for (int p = 0; p < MT; ++p) {
      if constexpr (AF32) {
        fa[p][0] = *(const float4*)(Af + (size_t)(bm + sr + p * 32) * K + k0 + sc);
        fa[p][1] = *(const float4*)(Af + (size_t)(bm + sr + p * 32) * K + k0 + sc + 4);
      } else {
        ua[p] = *(const uint4*)(Ab + (size_t)(bm + sr + p * 32) * K + k0 + sc);
      }
    }
#pragma unroll
    for (int p = 0; p < 4; ++p)
      ub[p] = *(const uint4*)(Bt + (size_t)(bn + sr + p * 32) * K + k0 + sc);
  };

  load_chunk(0);

  for (int k0 = 0; k0 < K; k0 += 64) {
    __syncthreads();  // BAR-A: prev-tile LDS reads done; vmcnt drain = our staged data
#pragma unroll
    for (int p = 0; p < MT; ++p) {
      if constexpr (AF32) {
        uint4 u;
        u.x = pkbf(fa[p][0].x, fa[p][0].y);
        u.y = pkbf(fa[p][0].z, fa[p][0].w);
        u.z = pkbf(fa[p][1].x, fa[p][1].y);
        u.w = pkbf(fa[p][1].z, fa[p][1].w);
        *(uint4*)(&As[sr + p * 32][sc]) = u;
      } else {
        *(uint4*)(&As[sr + p * 32][sc]) = ua[p];
      }
    }
#pragma unroll
    for (int p = 0; p < 4; ++p)
      *(uint4*)(&Bs[sr + p * 32][sc]) = ub[p];
    if (k0 + 64 < K) load_chunk(k0 + 64);  // prefetch: lands during compute
    asm volatile("s_waitcnt lgkmcnt(0)" ::: "memory");
    __builtin_amdgcn_s_barrier();  // BAR-B (no vmcnt drain -> prefetch stays in flight)
#pragma unroll
    for (int kk = 0; kk < 2; ++kk) {
      short8 af[MT], bfr[4];
#pragma unroll
      for (int mt = 0; mt < MT; ++mt)
        af[mt] = *(const short8*)(&As[wr + mt * 16 + l15][kk * 32 + lq * 8]);
#pragma unroll
      for (int nt = 0; nt < 4; ++nt)
        bfr[nt] = *(const short8*)(&Bs[wc + nt * 16 + l15][kk * 32 + lq * 8]);
#pragma unroll
      for (int mt = 0; mt < MT; ++mt)
#pragma unroll
        for (int nt = 0; nt < 4; ++nt)
          acc[mt][nt] = __builtin_amdgcn_mfma_f32_16x16x32_bf16(af[mt], bfr[nt], acc[mt][nt], 0, 0, 0);
    }
  }

#pragma unroll
  for (int mt = 0; mt < MT; ++mt)
#pragma unroll
    for (int nt = 0; nt < 4; ++nt)
#pragma unroll
      for (int j = 0; j < 4; ++j) {
        int row = bm + wr + mt * 16 + lq * 4 + j;
        int col = bn + wc + nt * 16 + l15;
        float v = acc[mt][nt][j];
        if constexpr (MODE == 0) {
          ((unsigned short*)C0)[(size_t)row * N + col] = f2bf(v * oscale);
        } else if constexpr (MODE == 1) {
          if (col < 512) {
            ((unsigned short*)C0)[(size_t)row * 512 + col] = f2bf(v);
          } else {
            int bb = row >> 11, m = row & 2047;
            int hd = col - 512;  // h*64+d
            C1[((size_t)bb * 512 + hd) * 2048 + m] = f2bf(v);
          }
        } else {
          ((float*)C0)[(size_t)row * N + col] = v + bias[col];
        }
      }
}

// Flash attention, swapped-MFMA in-register softmax, T14 async staging.
// Q (pre-scaled by scale*log2e) / K: [B*2048, 512] bf16. Vt: [b,h,d,m] bf16.
// Mask as packed 64-bit words (one per 64-key tile).
// 4 waves x 16 q-rows = 64 q-rows/block, KV tile 64; 256 threads.
// blockIdx.x = bh (fast-varying -> per-XCD K/V L2 residency), blockIdx.y = q-chunk.
__global__ __launch_bounds__(256, 4) void attn_kernel(
    const unsigned short* __restrict__ Q, const unsigned short* __restrict__ Kb,
    const unsigned short* __restrict__ Vt, const unsigned long long* __restrict__ Mpk,
    unsigned short* __restrict__ O) {
  __shared__ unsigned short Ks[64][72];
  __shared__ unsigned short Vs[64][72];
  const int b = blockIdx.x >> 3, h = blockIdx.x & 7;
  const int tid = threadIdx.x, wave = tid >> 6, lane = tid & 63;
  const int l15 = lane & 15, lq = lane >> 4;
  const int wrow = blockIdx.y * 64 + wave * 16;

  // Q fragments: lane holds q-col = l15, d-elems lq*8..+7
  short8 qf[2];
#pragma unroll
  for (int kk = 0; kk < 2; ++kk)
    qf[kk] = *(const short8*)(Q + (size_t)(b * 2048 + wrow + l15) * 512
                                + h * 64 + kk * 32 + lq * 8);

  f32x4 o[4] = {};  // O^T[d = dt*16+lq*4+j][q = l15]
  float mrun = -1e30f, lrun = 0.f;

  const unsigned short* Kg = Kb + (size_t)b * 2048 * 512 + h * 64;
  const unsigned short* Vg = Vt + (size_t)(b * 8 + h) * 64 * 2048;
  const unsigned long long* mp = Mpk + b * 32;

  const int str = tid >> 3;        // 0..31
  const int stc = (tid & 7) * 8;   // elem col within 64

  uint4 kreg[2], vreg[2];
  unsigned long long mreg;

  auto stage_load = [&](int mb) {
#pragma unroll
    for (int i = 0; i < 2; ++i)
      kreg[i] = *(const uint4*)(Kg + (size_t)(mb + str + i * 32) * 512 + stc);
#pragma unroll
    for (int i = 0; i < 2; ++i)
      vreg[i] = *(const uint4*)(Vg + (size_t)(str + i * 32) * 2048 + mb + stc);
    mreg = mp[mb >> 6];
  };

  stage_load(0);

  for (int mb = 0; mb < 2048; mb += 64) {
    __syncthreads();  // BAR-A: prev compute's LDS reads done; drains our staged loads
#pragma unroll
    for (int i = 0; i < 2; ++i)
      *(uint4*)(&Ks[str + i * 32][stc]) = kreg[i];
#pragma unroll
    for (int i = 0; i < 2; ++i)
      *(uint4*)(&Vs[str + i * 32][stc]) = vreg[i];
    unsigned long long mcur = mreg;  // snapshot before prefetch overwrites
    if (mb + 64 < 2048) stage_load(mb + 64);  // prefetch, lands during compute
    asm volatile("s_waitcnt lgkmcnt(0)" ::: "memory");
    __builtin_amdgcn_s_barrier();  // BAR-B: tile visible; prefetch stays in flight

    // swapped QK^T: s[ct] = S^T[key = ct*16+lq*4+j][q = l15]
    f32x4 s[4] = {};
#pragma unroll
    for (int kk = 0; kk < 2; ++kk) {
      short8 kf[4];
#pragma unroll
      for (int ct = 0; ct < 4; ++ct)
        kf[ct] = *(const short8*)(&Ks[ct * 16 + l15][kk * 32 + lq * 8]);
#pragma unroll
      for (int ct = 0; ct < 4; ++ct)
        s[ct] = __builtin_amdgcn_mfma_f32_16x16x32_bf16(kf[ct], qf[kk], s[ct], 0, 0, 0);
    }

    // apply mask from scalar-ized bitmask: key = ct*16 + lq*4 + j
    unsigned int mlo = __builtin_amdgcn_readfirstlane((unsigned int)mcur);
    unsigned int mhi = __builtin_amdgcn_readfirstlane((unsigned int)(mcur >> 32));
#pragma unroll
    for (int ct = 0; ct < 4; ++ct) {
      unsigned int ch = ((ct < 2) ? mlo : mhi) >> ((ct & 1) * 16);  // scalar
      unsigned int nib = (ch >> (lq * 4)) & 0xFu;
#pragma unroll
      for (int j = 0; j < 4; ++j)
        s[ct][j] = (nib & (1u << j)) ? s[ct][j] : -1e30f;
    }

    float t = -1e30f;
#pragma unroll
    for (int ct = 0; ct < 4; ++ct)
#pragma unroll
      for (int j = 0; j < 4; ++j)
        t = fmaxf(t, s[ct][j]);
    t = fmaxf(t, __shfl_xor(t, 16));
    t = fmaxf(t, __shfl_xor(t, 32));
    float mn = fmaxf(mrun, t);
    float fac = __builtin_amdgcn_exp2f(mrun - mn);
    mrun = mn;
    float rs = 0.f;
    unsigned int xp[4][2];  // bf16 pairs: keys ct*16+lq*4+{2p,2p+1}
#pragma unroll
    for (int ct = 0; ct < 4; ++ct) {
      float p0 = __builtin_amdgcn_exp2f(s[ct][0] - mn);
      float p1 = __builtin_amdgcn_exp2f(s[ct][1] - mn);
      float p2 = __builtin_amdgcn_exp2f(s[ct][2] - mn);
      float p3 = __builtin_amdgcn_exp2f(s[ct][3] - mn);
      rs += (p0 + p1) + (p2 + p3);
      xp[ct][0] = pkbf(p0, p1);
      xp[ct][1] = pkbf(p2, p3);
    }
    rs += __shfl_xor(rs, 16);
    rs += __shfl_xor(rs, 32);
    lrun = lrun * fac + rs;
#pragma unroll
    for (int dt = 0; dt < 4; ++dt)
#pragma unroll
      for (int j = 0; j < 4; ++j)
        o[dt][j] *= fac;

    // redistribute P^T into PV B-fragments:
    // dest reg r needs xp[kk*2 + (lq>>1)][r&1] from lane ((lq&1)*2 + (r>>1))*16 + l15
    unsigned int pf[2][4];
    const int slbase = ((lq & 1) * 2) * 16 + l15;
#pragma unroll
    for (int kk = 0; kk < 2; ++kk)
#pragma unroll
      for (int r = 0; r < 4; ++r) {
        int sl = (slbase + (r >> 1) * 16) << 2;
        unsigned a0 = (unsigned)__builtin_amdgcn_ds_bpermute(sl, (int)xp[kk * 2 + 0][r & 1]);
        unsigned a1 = (unsigned)__builtin_amdgcn_ds_bpermute(sl, (int)xp[kk * 2 + 1][r & 1]);
        pf[kk][r] = (lq >> 1) ? a1 : a0;
      }

    // PV swapped: O^T += V^T · P^T
#pragma unroll
    for (int kk = 0; kk < 2; ++kk) {
      union { unsigned int u[4]; short8 s8; } pc;
      pc.u[0] = pf[kk][0];
      pc.u[1] = pf[kk][1];
      pc.u[2] = pf[kk][2];
      pc.u[3] = pf[kk][3];
#pragma unroll
      for (int dt = 0; dt < 4; ++dt) {
        short8 vf = *(const short8*)(&Vs[dt * 16 + l15][kk * 32 + lq * 8]);
        o[dt] = __builtin_amdgcn_mfma_f32_16x16x32_bf16(vf, pc.s8, o[dt], 0, 0, 0);
      }
    }
  }

  float rl = 1.0f / lrun;
  unsigned short* Orow = O + (size_t)(b * 2048 + wrow + l15) * 512 + h * 64;
#pragma unroll
  for (int dt = 0; dt < 4; ++dt) {
    *(unsigned int*)(Orow + dt * 16 + lq * 4)     = pkbf(o[dt][0] * rl, o[dt][1] * rl);
    *(unsigned int*)(Orow + dt * 16 + lq * 4 + 2) = pkbf(o[dt][2] * rl, o[dt][3] * rl);
  }
}

extern "C" void kernel_launch(void* const* d_in, const int* in_sizes, int n_in,
                              void* d_out, int out_size, void* d_ws, size_t ws_size,
                              hipStream_t stream) {
  const float* x       = (const float*)d_in[0];
  const float* context = (const float*)d_in[1];
  const int*   mask    = (const int*)d_in[2];
  const float* Wq      = (const float*)d_in[3];
  const float* Wkv     = (const float*)d_in[4];
  const float* Wo      = (const float*)d_in[5];
  const float* bo      = (const float*)d_in[6];
  float* out = (float*)d_out;

  char* ws = (char*)d_ws;
  unsigned short* Wq_t  = (unsigned short*)(ws + 0);         //  512x512  bf16
  unsigned short* Wkv_t = (unsigned short*)(ws + 524288);    // 1024x512  bf16
  unsigned short* Wo_t  = (unsigned short*)(ws + 1572864);   //  512x512  bf16
  unsigned short* qb    = (unsigned short*)(ws + 2097152);   // 8192x512  bf16
  unsigned short* kb    = (unsigned short*)(ws + 10485760);  // 8192x512  bf16
  unsigned short* vtb   = (unsigned short*)(ws + 18874368);  // (b,h,d)x2048 bf16
  unsigned short* ab    = (unsigned short*)(ws + 27262976);  // 8192x512  bf16
  unsigned long long* mpk = (unsigned long long*)(ws + 35651584);  // 128 x u64

  const float QSCALE = 0.125f * 1.44269504088896f;  // head_dim^-0.5 * log2(e)

  tcast_kernel<<<dim3(8, 8), 256, 0, stream>>>(Wq, Wq_t, 512, 512);
  tcast_kernel<<<dim3(16, 8), 256, 0, stream>>>(Wkv, Wkv_t, 512, 1024);
  tcast_kernel<<<dim3(8, 8), 256, 0, stream>>>(Wo, Wo_t, 512, 512);
  maskpack_kernel<<<dim3(128), 64, 0, stream>>>(mask, mpk);
  gemm_kernel<4, 0, true><<<dim3(4, 64), 256, 0, stream>>>(x, Wq_t, qb, nullptr, nullptr, 8192, 512, 512, QSCALE);
  gemm_kernel<4, 1, true><<<dim3(8, 64), 256, 0, stream>>>(context, Wkv_t, kb, vtb, nullptr, 8192, 1024, 512, 1.0f);
  attn_kernel<<<dim3(32, 32), 256, 0, stream>>>(qb, kb, vtb, mpk, ab);
  gemm_kernel<4, 2, false><<<dim3(4, 64), 256, 0, stream>>>(ab, Wo_t, out, nullptr, bo, 8192, 512, 512, 1.0f);
}